// Round 1
// baseline (530.473 us; speedup 1.0000x reference)
//
#include <hip/hip_runtime.h>

// EdgeBlock: out[E,128] = concat(edges, nodes[recv], nodes[send]) @ W.T + b
// Strategy: bf16 MFMA GEMM (threshold 0.124 permits bf16; no fp32 MFMA on CDNA4).
// Block: 256 thr = 4 waves (2x2), tile 128x128, K=384 in 12 chunks of 32.
// LDS double-buffered, stride 40 bf16 (16B-aligned rows, 2-way bank alias = free).

#define NODE_D 128
#define EDGE_D 128
#define IN_D   384
#define OUT_D  128
#define BM 128
#define BN 128
#define BK 32
#define SA 40          // padded LDS row stride (bf16 elems); 80B rows, 16B aligned
#define NCHUNK 12

typedef __attribute__((ext_vector_type(8))) short bf16x8;
typedef __attribute__((ext_vector_type(4))) float floatx4;

static __device__ __forceinline__ unsigned int pack_bf16x2(float lo, float hi) {
    unsigned int a = __builtin_bit_cast(unsigned int, lo);
    unsigned int b = __builtin_bit_cast(unsigned int, hi);
    a += 0x7fffu + ((a >> 16) & 1u);   // RNE
    b += 0x7fffu + ((b >> 16) & 1u);
    return (a >> 16) | (b & 0xffff0000u);
}

__global__ __launch_bounds__(256, 2)
void edgeblock_gemm(const float* __restrict__ nodes,
                    const float* __restrict__ edges,
                    const int*   __restrict__ recv,
                    const int*   __restrict__ send,
                    const float* __restrict__ W,
                    const float* __restrict__ bias,
                    float*       __restrict__ out,
                    int E)
{
    __shared__ __align__(16) unsigned short As[2][BM * SA];
    __shared__ __align__(16) unsigned short Bs[2][BN * SA];

    const int tid   = threadIdx.x;
    const int lane8 = tid & 7;        // column group within a row (8 x float4 = 32 floats)
    const int h     = tid >> 3;       // 0..31 : row group
    const int wave  = tid >> 6;       // 0..3
    const int lane  = tid & 63;
    const int quad  = lane >> 4;
    const int l16   = lane & 15;
    const int wm    = (wave >> 1) * 64;   // wave's M offset in tile
    const int wn    = (wave & 1) * 64;    // wave's N offset in tile
    const long e0   = (long)blockIdx.x * BM;

    // Per-thread source row bases (4 rows each: h + 32*i). Clamp tail rows.
    const float* baseE[4];
    const float* baseR[4];
    const float* baseS[4];
    #pragma unroll
    for (int i = 0; i < 4; ++i) {
        long e = e0 + h + 32 * i;
        if (e > (long)E - 1) e = (long)E - 1;
        baseE[i] = edges + e * (long)EDGE_D;
        baseR[i] = nodes + (long)recv[e] * NODE_D;
        baseS[i] = nodes + (long)send[e] * NODE_D;
    }

    float4 va[4], vb[4];

    auto loadChunk = [&](int c) {
        const int col = (c & 3) * 32;
        #pragma unroll
        for (int i = 0; i < 4; ++i) {
            const float* src = (c < 4) ? baseE[i] : (c < 8) ? baseR[i] : baseS[i];
            va[i] = *(const float4*)(src + col + lane8 * 4);
            vb[i] = *(const float4*)(W + (long)(h + 32 * i) * IN_D + c * 32 + lane8 * 4);
        }
    };
    auto writeChunk = [&](int buf) {
        #pragma unroll
        for (int i = 0; i < 4; ++i) {
            uint2 pa, pb;
            pa.x = pack_bf16x2(va[i].x, va[i].y);
            pa.y = pack_bf16x2(va[i].z, va[i].w);
            pb.x = pack_bf16x2(vb[i].x, vb[i].y);
            pb.y = pack_bf16x2(vb[i].z, vb[i].w);
            *(uint2*)&As[buf][(h + 32 * i) * SA + lane8 * 4] = pa;
            *(uint2*)&Bs[buf][(h + 32 * i) * SA + lane8 * 4] = pb;
        }
    };

    floatx4 acc[4][4] = {};   // 16 frags: 64 AGPRs

    loadChunk(0);
    writeChunk(0);
    __syncthreads();

    #pragma unroll
    for (int c = 0; c < NCHUNK; ++c) {
        if (c + 1 < NCHUNK) loadChunk(c + 1);   // global loads in flight during MFMA
        const int buf = c & 1;

        bf16x8 af[4], bfr[4];
        #pragma unroll
        for (int mi = 0; mi < 4; ++mi)
            af[mi] = *(const bf16x8*)&As[buf][(wm + mi * 16 + l16) * SA + quad * 8];
        #pragma unroll
        for (int ni = 0; ni < 4; ++ni)
            bfr[ni] = *(const bf16x8*)&Bs[buf][(wn + ni * 16 + l16) * SA + quad * 8];
        #pragma unroll
        for (int mi = 0; mi < 4; ++mi)
            #pragma unroll
            for (int ni = 0; ni < 4; ++ni)
                acc[mi][ni] = __builtin_amdgcn_mfma_f32_16x16x32_bf16(
                    af[mi], bfr[ni], acc[mi][ni], 0, 0, 0);

        if (c + 1 < NCHUNK) writeChunk((c + 1) & 1);
        __syncthreads();
    }

    // Epilogue: C/D layout col = lane&15, row = quad*4 + reg
    float bv[4];
    #pragma unroll
    for (int ni = 0; ni < 4; ++ni) bv[ni] = bias[wn + ni * 16 + l16];

    #pragma unroll
    for (int mi = 0; mi < 4; ++mi) {
        #pragma unroll
        for (int r = 0; r < 4; ++r) {
            long row = e0 + wm + mi * 16 + quad * 4 + r;
            if (row < (long)E) {
                float* orow = out + row * (long)OUT_D + wn + l16;
                #pragma unroll
                for (int ni = 0; ni < 4; ++ni)
                    orow[ni * 16] = acc[mi][ni][r] + bv[ni];
            }
        }
    }
}

extern "C" void kernel_launch(void* const* d_in, const int* in_sizes, int n_in,
                              void* d_out, int out_size, void* d_ws, size_t ws_size,
                              hipStream_t stream) {
    const float* nodes = (const float*)d_in[0];
    const float* edges = (const float*)d_in[1];
    const int*   recv  = (const int*)d_in[2];
    const int*   send  = (const int*)d_in[3];
    const float* W     = (const float*)d_in[4];
    const float* bias  = (const float*)d_in[5];
    float* out = (float*)d_out;

    const int E = in_sizes[2];                 // 500000
    const int grid = (E + BM - 1) / BM;        // 3907

    edgeblock_gemm<<<grid, 256, 0, stream>>>(nodes, edges, recv, send, W, bias, out, E);
}

// Round 2
// 524.476 us; speedup vs baseline: 1.0114x; 1.0114x over previous
//
#include <hip/hip_runtime.h>

// EdgeBlock v2: out[E,128] = concat(edges, nodes[recv], nodes[send]) @ W.T + b
// Round-2 restructure (latency-bound fix):
//  - pre-pass converts nodes + W to bf16 in d_ws (halves gather bytes; W L2-resident)
//  - node-gather chunks staged via async global_load_lds_dwordx4 (no VGPR round trip)
//  - B-fragments load straight from L2 (no B LDS), prefetched 1 chunk ahead
//  - XOR block swizzle (phys = s ^ ((row>>1)&3)) since global_load_lds forbids padding;
//    gives 2-way bank aliasing on ds_read_b128 (free per m136)

#define BM 128
#define NCH 12

typedef __attribute__((ext_vector_type(8))) short bf16x8;
typedef __attribute__((ext_vector_type(4))) float floatx4;
typedef __attribute__((ext_vector_type(4))) unsigned int uint4v;

#define GLOAD_LDS16(g, l) __builtin_amdgcn_global_load_lds(                    \
    (const __attribute__((address_space(1))) unsigned int*)(g),                \
    (__attribute__((address_space(3))) unsigned int*)(l), 16, 0, 0)

static __device__ __forceinline__ unsigned int pack_bf16x2(float lo, float hi) {
    unsigned int a = __builtin_bit_cast(unsigned int, lo);
    unsigned int b = __builtin_bit_cast(unsigned int, hi);
    a += 0x7fffu + ((a >> 16) & 1u);   // RNE
    b += 0x7fffu + ((b >> 16) & 1u);
    return (a >> 16) | (b & 0xffff0000u);
}

// ---------- pre-pass: fp32 -> bf16 (float4 -> 8B) ----------
__global__ void cvt_bf16(const float* __restrict__ src, unsigned int* __restrict__ dst, int n4) {
    int i = blockIdx.x * blockDim.x + threadIdx.x;
    if (i < n4) {
        float4 v = ((const float4*)src)[i];
        uint2 p;
        p.x = pack_bf16x2(v.x, v.y);
        p.y = pack_bf16x2(v.z, v.w);
        ((uint2*)dst)[i] = p;
    }
}

// ---------- main GEMM ----------
__global__ __launch_bounds__(256, 2)
void edge_gemm_v2(const float* __restrict__ edges,
                  const int*   __restrict__ recv,
                  const int*   __restrict__ send,
                  const unsigned short* __restrict__ nodes_bf,
                  const unsigned short* __restrict__ w_bf,
                  const float* __restrict__ bias,
                  float*       __restrict__ out,
                  int E)
{
    // 128 rows x 32 bf16 (64B) per buffer, double-buffered. No padding (global_load_lds),
    // 16B blocks XOR-swizzled by ((row>>1)&3).
    __shared__ __align__(16) unsigned short As[2][BM * 32];

    const int tid  = threadIdx.x;
    const int wave = tid >> 6, lane = tid & 63;
    const int quad = lane >> 4, l16 = lane & 15;
    const int wm = (wave >> 1) * 64, wn = (wave & 1) * 64;
    const long e0 = (long)blockIdx.x * BM;

    // --- node-gather geometry: wave w stages rows [w*32, w*32+32) via 2 wave-insts ---
    const int rl   = lane >> 2;                      // row within 16-row group
    const int sblk = (lane & 3) ^ ((lane >> 3) & 3); // source 16B-block for this lane (swizzle)
    long er0 = e0 + wave * 32 + rl;      if (er0 > (long)E - 1) er0 = (long)E - 1;
    long er1 = e0 + wave * 32 + 16 + rl; if (er1 > (long)E - 1) er1 = (long)E - 1;
    const unsigned short* gR0 = nodes_bf + (long)recv[er0] * 128 + sblk * 8;
    const unsigned short* gR1 = nodes_bf + (long)recv[er1] * 128 + sblk * 8;
    const unsigned short* gS0 = nodes_bf + (long)send[er0] * 128 + sblk * 8;
    const unsigned short* gS1 = nodes_bf + (long)send[er1] * 128 + sblk * 8;

    // --- edge staging geometry: thread t handles row t>>1, phys blocks {b0, b0+1} ---
    const int erow = tid >> 1;
    long ee = e0 + erow; if (ee > (long)E - 1) ee = (long)E - 1;
    const float* eptr = edges + ee * 128L;
    const int swzE = (erow >> 1) & 3;
    const int b0 = (tid & 1) * 2;
    const int s0 = b0 ^ swzE, s1 = (b0 + 1) ^ swzE;

    floatx4 acc[4][4] = {};
    float4 ev[4];

    auto edge_issue = [&](int c) {
        const float* p = eptr + c * 32;
        ev[0] = *(const float4*)(p + s0 * 8);
        ev[1] = *(const float4*)(p + s0 * 8 + 4);
        ev[2] = *(const float4*)(p + s1 * 8);
        ev[3] = *(const float4*)(p + s1 * 8 + 4);
    };
    auto edge_write = [&](int buf) {
        uint4v w0, w1;
        w0.x = pack_bf16x2(ev[0].x, ev[0].y); w0.y = pack_bf16x2(ev[0].z, ev[0].w);
        w0.z = pack_bf16x2(ev[1].x, ev[1].y); w0.w = pack_bf16x2(ev[1].z, ev[1].w);
        w1.x = pack_bf16x2(ev[2].x, ev[2].y); w1.y = pack_bf16x2(ev[2].z, ev[2].w);
        w1.z = pack_bf16x2(ev[3].x, ev[3].y); w1.w = pack_bf16x2(ev[3].z, ev[3].w);
        *(uint4v*)&As[buf][erow * 32 + b0 * 8]       = w0;
        *(uint4v*)&As[buf][erow * 32 + (b0 + 1) * 8] = w1;
    };
    auto node_issue = [&](int c, int buf) {    // c in 4..11
        const int off = (c & 3) * 32;          // ushort offset within bf16 node row
        const unsigned short* g0 = (c < 8) ? gR0 : gS0;
        const unsigned short* g1 = (c < 8) ? gR1 : gS1;
        GLOAD_LDS16(g0 + off, &As[buf][(wave * 2 + 0) * 512]);
        GLOAD_LDS16(g1 + off, &As[buf][(wave * 2 + 1) * 512]);
    };

    bf16x8 bcur[4], bnext[4];
    auto loadB = [&](int c, bf16x8* b) {
        #pragma unroll
        for (int ni = 0; ni < 4; ++ni)
            b[ni] = *(const bf16x8*)(w_bf + (long)(wn + ni * 16 + l16) * 384 + c * 32 + quad * 8);
    };

    // prolog: stage chunk 0 (edges), load B(0)
    edge_issue(0);
    loadB(0, bcur);
    edge_write(0);
    __syncthreads();

    #pragma unroll
    for (int c = 0; c < NCH; ++c) {
        const int buf = c & 1;
        if (c + 1 < NCH) {
            if (c + 1 < 4) edge_issue(c + 1);
            else           node_issue(c + 1, buf ^ 1);
            loadB(c + 1, bnext);
        }
        bf16x8 af[4];
        #pragma unroll
        for (int mi = 0; mi < 4; ++mi)
            af[mi] = *(const bf16x8*)&As[buf][(wm + mi * 16 + l16) * 32 +
                                             ((quad ^ ((l16 >> 1) & 3)) * 8)];
        #pragma unroll
        for (int mi = 0; mi < 4; ++mi)
            #pragma unroll
            for (int ni = 0; ni < 4; ++ni)
                acc[mi][ni] = __builtin_amdgcn_mfma_f32_16x16x32_bf16(
                    af[mi], bcur[ni], acc[mi][ni], 0, 0, 0);
        if (c + 1 < NCH) {
            if (c + 1 < 4) edge_write(buf ^ 1);
            #pragma unroll
            for (int ni = 0; ni < 4; ++ni) bcur[ni] = bnext[ni];
        }
        __syncthreads();
    }

    // epilogue: C/D layout col = lane&15, row = quad*4 + reg
    float bv[4];
    #pragma unroll
    for (int ni = 0; ni < 4; ++ni) bv[ni] = bias[wn + ni * 16 + l16];
    #pragma unroll
    for (int mi = 0; mi < 4; ++mi) {
        #pragma unroll
        for (int r = 0; r < 4; ++r) {
            long row = e0 + wm + mi * 16 + quad * 4 + r;
            if (row < (long)E) {
                float* orow = out + row * 128L + wn + l16;
                #pragma unroll
                for (int ni = 0; ni < 4; ++ni)
                    orow[ni * 16] = acc[mi][ni][r] + bv[ni];
            }
        }
    }
}

// ---------- fallback (round-1 kernel, used only if ws too small) ----------
#define SA 40
typedef __attribute__((ext_vector_type(8))) short bf16x8f;

__global__ __launch_bounds__(256, 2)
void edgeblock_gemm_fb(const float* __restrict__ nodes,
                       const float* __restrict__ edges,
                       const int*   __restrict__ recv,
                       const int*   __restrict__ send,
                       const float* __restrict__ W,
                       const float* __restrict__ bias,
                       float*       __restrict__ out,
                       int E)
{
    __shared__ __align__(16) unsigned short Asf[2][BM * SA];
    __shared__ __align__(16) unsigned short Bsf[2][BM * SA];
    const int tid = threadIdx.x;
    const int lane8 = tid & 7, h = tid >> 3;
    const int wave = tid >> 6, lane = tid & 63;
    const int quad = lane >> 4, l16 = lane & 15;
    const int wm = (wave >> 1) * 64, wn = (wave & 1) * 64;
    const long e0 = (long)blockIdx.x * BM;
    const float *baseE[4], *baseR[4], *baseS[4];
    #pragma unroll
    for (int i = 0; i < 4; ++i) {
        long e = e0 + h + 32 * i;
        if (e > (long)E - 1) e = (long)E - 1;
        baseE[i] = edges + e * 128L;
        baseR[i] = nodes + (long)recv[e] * 128;
        baseS[i] = nodes + (long)send[e] * 128;
    }
    float4 va[4], vb[4];
    auto loadChunk = [&](int c) {
        const int col = (c & 3) * 32;
        #pragma unroll
        for (int i = 0; i < 4; ++i) {
            const float* src = (c < 4) ? baseE[i] : (c < 8) ? baseR[i] : baseS[i];
            va[i] = *(const float4*)(src + col + lane8 * 4);
            vb[i] = *(const float4*)(W + (long)(h + 32 * i) * 384 + c * 32 + lane8 * 4);
        }
    };
    auto writeChunk = [&](int buf) {
        #pragma unroll
        for (int i = 0; i < 4; ++i) {
            uint2 pa, pb;
            pa.x = pack_bf16x2(va[i].x, va[i].y);
            pa.y = pack_bf16x2(va[i].z, va[i].w);
            pb.x = pack_bf16x2(vb[i].x, vb[i].y);
            pb.y = pack_bf16x2(vb[i].z, vb[i].w);
            *(uint2*)&Asf[buf][(h + 32 * i) * SA + lane8 * 4] = pa;
            *(uint2*)&Bsf[buf][(h + 32 * i) * SA + lane8 * 4] = pb;
        }
    };
    floatx4 acc[4][4] = {};
    loadChunk(0); writeChunk(0); __syncthreads();
    #pragma unroll
    for (int c = 0; c < NCH; ++c) {
        if (c + 1 < NCH) loadChunk(c + 1);
        const int buf = c & 1;
        bf16x8f af[4], bfr[4];
        #pragma unroll
        for (int mi = 0; mi < 4; ++mi)
            af[mi] = *(const bf16x8f*)&Asf[buf][(wm + mi * 16 + l16) * SA + quad * 8];
        #pragma unroll
        for (int ni = 0; ni < 4; ++ni)
            bfr[ni] = *(const bf16x8f*)&Bsf[buf][(wn + ni * 16 + l16) * SA + quad * 8];
        #pragma unroll
        for (int mi = 0; mi < 4; ++mi)
            #pragma unroll
            for (int ni = 0; ni < 4; ++ni)
                acc[mi][ni] = __builtin_amdgcn_mfma_f32_16x16x32_bf16(
                    af[mi], bfr[ni], acc[mi][ni], 0, 0, 0);
        if (c + 1 < NCH) writeChunk((c + 1) & 1);
        __syncthreads();
    }
    float bv[4];
    #pragma unroll
    for (int ni = 0; ni < 4; ++ni) bv[ni] = bias[wn + ni * 16 + l16];
    #pragma unroll
    for (int mi = 0; mi < 4; ++mi)
        #pragma unroll
        for (int r = 0; r < 4; ++r) {
            long row = e0 + wm + mi * 16 + quad * 4 + r;
            if (row < (long)E) {
                float* orow = out + row * 128L + wn + l16;
                #pragma unroll
                for (int ni = 0; ni < 4; ++ni)
                    orow[ni * 16] = acc[mi][ni][r] + bv[ni];
            }
        }
}

extern "C" void kernel_launch(void* const* d_in, const int* in_sizes, int n_in,
                              void* d_out, int out_size, void* d_ws, size_t ws_size,
                              hipStream_t stream) {
    const float* nodes = (const float*)d_in[0];
    const float* edges = (const float*)d_in[1];
    const int*   recv  = (const int*)d_in[2];
    const int*   send  = (const int*)d_in[3];
    const float* W     = (const float*)d_in[4];
    const float* bias  = (const float*)d_in[5];
    float* out = (float*)d_out;

    const int E = in_sizes[2];
    const int grid = (E + BM - 1) / BM;

    const size_t nodes_bytes = (size_t)in_sizes[0] * 2;          // bf16 nodes
    const size_t need = nodes_bytes + (size_t)in_sizes[4] * 2;   // + bf16 W
    if (ws_size < need) {
        edgeblock_gemm_fb<<<grid, 256, 0, stream>>>(nodes, edges, recv, send, W, bias, out, E);
        return;
    }

    unsigned short* nodes_bf = (unsigned short*)d_ws;
    unsigned short* w_bf     = (unsigned short*)((char*)d_ws + nodes_bytes);

    const int n4n = in_sizes[0] / 4;
    cvt_bf16<<<(n4n + 255) / 256, 256, 0, stream>>>(nodes, (unsigned int*)nodes_bf, n4n);
    const int n4w = in_sizes[4] / 4;
    cvt_bf16<<<(n4w + 255) / 256, 256, 0, stream>>>(W, (unsigned int*)w_bf, n4w);

    edge_gemm_v2<<<grid, 256, 0, stream>>>(edges, recv, send, nodes_bf, w_bf, bias, out, E);
}